// Round 7
// baseline (45.405 us; speedup 1.0000x reference)
//
#include <hip/hip_runtime.h>

#define CIN 16
#define COUT 32
#define NB 8
#define HW 4096
#define PPW 66                 // padded image width
#define PPA (66 * 66)          // padded pixels per image
#define KF 160                 // features per pixel: 16ch * 10 (silu, T1..T8, zero)

typedef short bf16x8 __attribute__((ext_vector_type(8)));
typedef float f32x4 __attribute__((ext_vector_type(4)));

__device__ inline unsigned short f2bf(float f) {
    unsigned u = __builtin_bit_cast(unsigned, f);
    u += 0x7FFFu + ((u >> 16) & 1u);            // RNE
    return (unsigned short)(u >> 16);
}
__device__ inline unsigned pk(float a, float b) {
    return (unsigned)f2bf(a) | ((unsigned)f2bf(b) << 16);
}

#define FEAT_N (16 * PPA)                 // 69696 feature threads
#define FB ((FEAT_N + 255) / 256)         // 273 blocks
#define WF_N (9 * COUT * KF)              // 46080 weight elems (= 90 frags * 64 lanes * 8)
#define WB ((WF_N + 255) / 256)           // 180 blocks

// ---------- Fused prep: features (blocks <FB) + fragment-linear weight fold ----------
// wfl layout: frag = (shift*5 + st)*2 + f  (f: 0 = couts 0-15, 1 = couts 16-31)
//             wfl[frag*512 + lane*8 + e] = Wf[shift][o = f*16 + (lane&15)]
//                                            [kel = st*32 + (lane>>4)*8 + e]
__global__ __launch_bounds__(256) void kan_prep(const float* __restrict__ x,
                                                const float* __restrict__ w,
                                                const float* __restrict__ c,
                                                unsigned short* __restrict__ g2,
                                                unsigned short* __restrict__ wfl) {
    if (blockIdx.x < FB) {
        const int t = blockIdx.x * 256 + threadIdx.x;
        if (t >= FEAT_N) return;
        const int b  = t / PPA;
        const int pp = t - b * PPA;
        const int py = pp / PPW;
        const int px = pp - py * PPW;

        unsigned rw[KF / 2];
        const bool interior = (py >= 1) & (py <= 64) & (px >= 1) & (px <= 64);
        if (interior) {
            const int pix = (py - 1) * 64 + (px - 1);
#pragma unroll
            for (int i = 0; i < CIN; ++i) {
                const float v  = x[((size_t)(b * CIN + i)) * HW + pix];
                const float p  = __expf(-v);
                const float p2 = p * p;
                const float s  = v * __builtin_amdgcn_rcpf(1.f + p);           // silu
                const float u  = (1.f - p2) * __builtin_amdgcn_rcpf(1.f + p2); // tanh
                const float u2 = 2.f * u;
                const float t1 = u;
                const float t2 = u2 * u - 1.f;
                const float t3 = u2 * t2 - t1;
                const float t4 = u2 * t3 - t2;
                const float t5 = u2 * t4 - t3;
                const float t6 = u2 * t5 - t4;
                const float t7 = u2 * t6 - t5;
                const float t8 = u2 * t7 - t6;
                rw[i * 5 + 0] = pk(s, t1);
                rw[i * 5 + 1] = pk(t2, t3);
                rw[i * 5 + 2] = pk(t4, t5);
                rw[i * 5 + 3] = pk(t6, t7);
                rw[i * 5 + 4] = (unsigned)f2bf(t8);   // hi half 0 (pad feature)
            }
        } else {
#pragma unroll
            for (int j = 0; j < KF / 2; ++j) rw[j] = 0u;
        }
        uint4* dst = (uint4*)(g2 + (size_t)t * KF);
#pragma unroll
        for (int q = 0; q < KF / 8; ++q)
            dst[q] = make_uint4(rw[4 * q], rw[4 * q + 1], rw[4 * q + 2], rw[4 * q + 3]);
    } else {
        const int t = (blockIdx.x - FB) * 256 + threadIdx.x;
        if (t >= WF_N) return;
        const int e    = t & 7;
        const int lane = (t >> 3) & 63;
        const int frag = t >> 9;              // 0..89
        const int shift = frag / 10;
        const int r     = frag % 10;
        const int st    = r >> 1;
        const int f     = r & 1;
        const int o     = f * 16 + (lane & 15);
        const int kel   = st * 32 + (lane >> 4) * 8 + e;
        const int i     = kel / 10, n = kel % 10;
        float val = 0.f;
        if (n != 9) {
            const float wv = w[(size_t)(i * COUT + o) * 9 + shift];
            val = (n == 0) ? wv : wv * c[((size_t)(i * COUT + o) * 9 + shift) * NB + (n - 1)];
        }
        wfl[t] = f2bf(val);
    }
}

// ---------- MFMA GEMM: 32 px/wave, each A-fragment feeds 4 MFMAs ----------
// Block = 256 thr = 4 waves = 2 output rows; wave wv: row y0+(wv>>1), px x0=(wv&1)*32.
// Weights LDS-staged in 2 phases (fragment-linear, conflict-free); B gathered from L2.
#define P0_FRAGS 50                        // shifts 0-4
#define P1_FRAGS 40                        // shifts 5-8
#define LDSE (P0_FRAGS * 512)              // 51.2 KB

__global__ __launch_bounds__(256, 2) void kan_gemm(const unsigned short* __restrict__ g2,
                                                   const unsigned short* __restrict__ wfl,
                                                   float* __restrict__ out) {
    __shared__ unsigned short ldsA[LDSE];

    const int bid = blockIdx.x;
    const int blk = ((bid & 7) << 6) | (bid >> 3);   // XCD swizzle: 2 images per XCD
    const int b   = blk >> 5;
    const int tid = threadIdx.x;
    const int l   = tid & 63;
    const int wv  = tid >> 6;
    const int y   = ((blk & 31) << 1) + (wv >> 1);
    const int col = l & 15;
    const int quad = l >> 4;
    const int x0  = (wv & 1) * 32;

    const unsigned short* abase = ldsA + l * 8;   // lane-linear A reads

    f32x4 acc00 = {0.f, 0.f, 0.f, 0.f};   // px group 0, couts 0-15
    f32x4 acc01 = {0.f, 0.f, 0.f, 0.f};   // px group 0, couts 16-31
    f32x4 acc10 = {0.f, 0.f, 0.f, 0.f};   // px group 1, couts 0-15
    f32x4 acc11 = {0.f, 0.f, 0.f, 0.f};   // px group 1, couts 16-31

    // ---- phase 0: shifts 0-4 ----
    for (int ch = tid; ch < P0_FRAGS * 64; ch += 256)
        *(uint4*)&ldsA[ch * 8] = *(const uint4*)&wfl[ch * 8];
    __syncthreads();

#pragma unroll
    for (int ss = 0; ss < 5; ++ss) {
        const int dy = ss / 3 - 1, dx = ss % 3 - 1;
        const int pp = b * PPA + (y + 1 + dy) * PPW + (x0 + col + 1 + dx);
        const unsigned short* bb0 = g2 + (size_t)pp * KF + quad * 8;
        const unsigned short* bb1 = bb0 + (size_t)16 * KF;
#pragma unroll
        for (int st = 0; st < 5; ++st) {
            const bf16x8 bf0 = *(const bf16x8*)(bb0 + st * 32);
            const bf16x8 bf1 = *(const bf16x8*)(bb1 + st * 32);
            const bf16x8 a0  = *(const bf16x8*)(abase + (ss * 10 + st * 2) * 512);
            const bf16x8 a1  = *(const bf16x8*)(abase + (ss * 10 + st * 2 + 1) * 512);
            acc00 = __builtin_amdgcn_mfma_f32_16x16x32_bf16(a0, bf0, acc00, 0, 0, 0);
            acc01 = __builtin_amdgcn_mfma_f32_16x16x32_bf16(a1, bf0, acc01, 0, 0, 0);
            acc10 = __builtin_amdgcn_mfma_f32_16x16x32_bf16(a0, bf1, acc10, 0, 0, 0);
            acc11 = __builtin_amdgcn_mfma_f32_16x16x32_bf16(a1, bf1, acc11, 0, 0, 0);
        }
    }
    __syncthreads();

    // ---- phase 1: shifts 5-8 ----
    for (int ch = tid; ch < P1_FRAGS * 64; ch += 256)
        *(uint4*)&ldsA[ch * 8] = *(const uint4*)&wfl[(size_t)P0_FRAGS * 512 + ch * 8];
    __syncthreads();

#pragma unroll
    for (int ss = 0; ss < 4; ++ss) {
        const int shift = 5 + ss;
        const int dy = shift / 3 - 1, dx = shift % 3 - 1;
        const int pp = b * PPA + (y + 1 + dy) * PPW + (x0 + col + 1 + dx);
        const unsigned short* bb0 = g2 + (size_t)pp * KF + quad * 8;
        const unsigned short* bb1 = bb0 + (size_t)16 * KF;
#pragma unroll
        for (int st = 0; st < 5; ++st) {
            const bf16x8 bf0 = *(const bf16x8*)(bb0 + st * 32);
            const bf16x8 bf1 = *(const bf16x8*)(bb1 + st * 32);
            const bf16x8 a0  = *(const bf16x8*)(abase + (ss * 10 + st * 2) * 512);
            const bf16x8 a1  = *(const bf16x8*)(abase + (ss * 10 + st * 2 + 1) * 512);
            acc00 = __builtin_amdgcn_mfma_f32_16x16x32_bf16(a0, bf0, acc00, 0, 0, 0);
            acc01 = __builtin_amdgcn_mfma_f32_16x16x32_bf16(a1, bf0, acc01, 0, 0, 0);
            acc10 = __builtin_amdgcn_mfma_f32_16x16x32_bf16(a0, bf1, acc10, 0, 0, 0);
            acc11 = __builtin_amdgcn_mfma_f32_16x16x32_bf16(a1, bf1, acc11, 0, 0, 0);
        }
    }

    float* op0 = out + (size_t)b * COUT * HW + y * 64 + x0 + col;
    float* op1 = op0 + 16;
#pragma unroll
    for (int r = 0; r < 4; ++r) {
        op0[(size_t)(quad * 4 + r) * HW]      = acc00[r];
        op0[(size_t)(quad * 4 + r + 16) * HW] = acc01[r];
        op1[(size_t)(quad * 4 + r) * HW]      = acc10[r];
        op1[(size_t)(quad * 4 + r + 16) * HW] = acc11[r];
    }
}

extern "C" void kernel_launch(void* const* d_in, const int* in_sizes, int n_in,
                              void* d_out, int out_size, void* d_ws, size_t ws_size,
                              hipStream_t stream) {
    const float* x = (const float*)d_in[0];
    const float* w = (const float*)d_in[1];
    const float* c = (const float*)d_in[2];
    float* out = (float*)d_out;

    unsigned short* g2  = (unsigned short*)d_ws;                       // 16*4356*160 bf16
    unsigned short* wfl = (unsigned short*)((char*)d_ws + (size_t)16 * PPA * KF * 2);

    kan_prep<<<FB + WB, 256, 0, stream>>>(x, w, c, g2, wfl);
    kan_gemm<<<512, 256, 0, stream>>>(g2, wfl, out);
}

// Round 8
// 35.252 us; speedup vs baseline: 1.2880x; 1.2880x over previous
//
#include <hip/hip_runtime.h>

#define CIN 16
#define COUT 32
#define NB 8
#define HW 4096
#define PPW 66                 // padded image width
#define PPA (66 * 66)          // padded pixels per image
#define KF 160                 // features per pixel: 16ch * 10 (silu, T1..T8, zero)
#define NCH 20                 // 16B chunks per pixel (KF/8)

typedef short bf16x8 __attribute__((ext_vector_type(8)));
typedef float f32x4 __attribute__((ext_vector_type(4)));

__device__ inline unsigned short f2bf(float f) {
    unsigned u = __builtin_bit_cast(unsigned, f);
    u += 0x7FFFu + ((u >> 16) & 1u);            // RNE
    return (unsigned short)(u >> 16);
}
__device__ inline unsigned pk(float a, float b) {
    return (unsigned)f2bf(a) | ((unsigned)f2bf(b) << 16);
}

#define FEAT_N4 (16 * 4 * PPA)            // 278784 threads: (b, cg, pp), 4 channels each
#define FB4 ((FEAT_N4 + 255) / 256)       // 1089 blocks
#define WF_N (9 * COUT * KF)              // 46080 weight elems (= 90 frags * 64 lanes * 8)
#define WB ((WF_N + 255) / 256)           // 180 blocks

// ---------- Prep: features chunk-major g2t[b][c][pp][8] + fragment-linear weights ----------
// Feature thread (b, cg, pp) computes channels 4cg..4cg+3 -> 40 bf16 -> chunks c=5cg..5cg+4.
// B-chunk c holds kel = 8c..8c+7 (kel = i*10 + n); gemm B-frag (st,quad) = chunk st*4+quad.
__global__ __launch_bounds__(256) void kan_prep(const float* __restrict__ x,
                                                const float* __restrict__ w,
                                                const float* __restrict__ c,
                                                unsigned short* __restrict__ g2t,
                                                unsigned short* __restrict__ wfl) {
    if (blockIdx.x < FB4) {
        const int t = blockIdx.x * 256 + threadIdx.x;
        if (t >= FEAT_N4) return;
        const int pp = t % PPA;           // fastest -> coalesced stores
        const int bc = t / PPA;
        const int cg = bc & 3;
        const int b  = bc >> 2;
        const int py = pp / PPW;
        const int px = pp - py * PPW;

        unsigned rw[20];
        const bool interior = (py >= 1) & (py <= 64) & (px >= 1) & (px <= 64);
        if (interior) {
            const int pix = (py - 1) * 64 + (px - 1);
#pragma unroll
            for (int j = 0; j < 4; ++j) {
                const int i = cg * 4 + j;
                const float v  = x[((size_t)(b * CIN + i)) * HW + pix];
                const float p  = __expf(-v);
                const float p2 = p * p;
                const float s  = v * __builtin_amdgcn_rcpf(1.f + p);           // silu
                const float u  = (1.f - p2) * __builtin_amdgcn_rcpf(1.f + p2); // tanh
                const float u2 = 2.f * u;
                const float t1 = u;
                const float t2 = u2 * u - 1.f;
                const float t3 = u2 * t2 - t1;
                const float t4 = u2 * t3 - t2;
                const float t5 = u2 * t4 - t3;
                const float t6 = u2 * t5 - t4;
                const float t7 = u2 * t6 - t5;
                const float t8 = u2 * t7 - t6;
                rw[j * 5 + 0] = pk(s, t1);
                rw[j * 5 + 1] = pk(t2, t3);
                rw[j * 5 + 2] = pk(t4, t5);
                rw[j * 5 + 3] = pk(t6, t7);
                rw[j * 5 + 4] = (unsigned)f2bf(t8);   // hi half 0 (pad feature)
            }
        } else {
#pragma unroll
            for (int j = 0; j < 20; ++j) rw[j] = 0u;
        }
        uint4* dst = (uint4*)g2t;
#pragma unroll
        for (int q = 0; q < 5; ++q)
            dst[((size_t)(b * NCH + cg * 5 + q)) * PPA + pp] =
                make_uint4(rw[4 * q], rw[4 * q + 1], rw[4 * q + 2], rw[4 * q + 3]);
    } else {
        const int t = (blockIdx.x - FB4) * 256 + threadIdx.x;
        if (t >= WF_N) return;
        const int e    = t & 7;
        const int lane = (t >> 3) & 63;
        const int frag = t >> 9;              // 0..89 = (shift*5 + st)*2 + f
        const int shift = frag / 10;
        const int r     = frag % 10;
        const int st    = r >> 1;
        const int f     = r & 1;
        const int o     = f * 16 + (lane & 15);
        const int kel   = st * 32 + (lane >> 4) * 8 + e;
        const int i     = kel / 10, n = kel % 10;
        float val = 0.f;
        if (n != 9) {
            const float wv = w[(size_t)(i * COUT + o) * 9 + shift];
            val = (n == 0) ? wv : wv * c[((size_t)(i * COUT + o) * 9 + shift) * NB + (n - 1)];
        }
        wfl[t] = f2bf(val);
    }
}

// ---------- MFMA GEMM: chunk-major B (4x256B segments/load), 3-phase LDS weights ----------
// Block = 256 thr = 4 waves = 1 output row; wave wv owns 16 px, all 32 cout.
#define PH_FRAGS 30                        // 3 shifts * 10 frags per phase
#define LDSE (PH_FRAGS * 512)              // 15360 bf16 = 30.7 KB

__global__ __launch_bounds__(256, 4) void kan_gemm(const unsigned short* __restrict__ g2t,
                                                   const unsigned short* __restrict__ wfl,
                                                   float* __restrict__ out) {
    __shared__ unsigned short ldsA[LDSE];

    const int bid = blockIdx.x;
    const int blk = ((bid & 7) << 7) | (bid >> 3);   // XCD swizzle: 2 images per XCD
    const int b   = blk >> 6;
    const int y   = blk & 63;
    const int tid = threadIdx.x;
    const int l   = tid & 63;
    const int wv  = tid >> 6;
    const int col = l & 15;
    const int quad = l >> 4;
    const int x0  = wv * 16;

    const unsigned short* abase = ldsA + l * 8;   // lane-linear A reads (conflict-free)

    f32x4 acc0 = {0.f, 0.f, 0.f, 0.f};
    f32x4 acc1 = {0.f, 0.f, 0.f, 0.f};

#pragma unroll
    for (int ph = 0; ph < 3; ++ph) {
        if (ph) __syncthreads();
        for (int ch = tid; ch < PH_FRAGS * 64; ch += 256)
            *(uint4*)&ldsA[ch * 8] = *(const uint4*)&wfl[((size_t)ph * PH_FRAGS * 64 + ch) * 8];
        __syncthreads();

#pragma unroll
        for (int ls = 0; ls < 3; ++ls) {
            const int shift = ph * 3 + ls;
            const int dy = shift / 3 - 1, dx = shift % 3 - 1;
            const int pp = (y + 1 + dy) * PPW + (x0 + col + 1 + dx);
            // chunk-major B: chunk c = st*4 + quad, lanes 0-15 consecutive pp
            const unsigned short* bq = g2t + (((size_t)b * NCH + quad) * PPA + pp) * 8;
#pragma unroll
            for (int st = 0; st < 5; ++st) {
                const bf16x8 bf = *(const bf16x8*)(bq + (size_t)st * 4 * PPA * 8);
                const bf16x8 a0 = *(const bf16x8*)(abase + (ls * 10 + st * 2) * 512);
                const bf16x8 a1 = *(const bf16x8*)(abase + (ls * 10 + st * 2 + 1) * 512);
                acc0 = __builtin_amdgcn_mfma_f32_16x16x32_bf16(a0, bf, acc0, 0, 0, 0);
                acc1 = __builtin_amdgcn_mfma_f32_16x16x32_bf16(a1, bf, acc1, 0, 0, 0);
            }
        }
    }

    float* op = out + (size_t)b * COUT * HW + y * 64 + x0 + col;
#pragma unroll
    for (int r = 0; r < 4; ++r) {
        op[(size_t)(quad * 4 + r) * HW]      = acc0[r];
        op[(size_t)(quad * 4 + r + 16) * HW] = acc1[r];
    }
}

extern "C" void kernel_launch(void* const* d_in, const int* in_sizes, int n_in,
                              void* d_out, int out_size, void* d_ws, size_t ws_size,
                              hipStream_t stream) {
    const float* x = (const float*)d_in[0];
    const float* w = (const float*)d_in[1];
    const float* c = (const float*)d_in[2];
    float* out = (float*)d_out;

    unsigned short* g2t = (unsigned short*)d_ws;                       // 16*20*4356*8 bf16 = 22.3 MB
    unsigned short* wfl = (unsigned short*)((char*)d_ws + (size_t)16 * PPA * KF * 2);

    kan_prep<<<FB4 + WB, 256, 0, stream>>>(x, w, c, g2t, wfl);
    kan_gemm<<<1024, 256, 0, stream>>>(g2t, wfl, out);
}